// Round 3
// baseline (796.630 us; speedup 1.0000x reference)
//
#include <hip/hip_runtime.h>

// Tanh-RNN: B=8192, T=2048, I=2, H=20, FC(H->1) on last h.
// Round 3: one wave per block; each wave runs TWO independent 8-row chains
// (16 rows/wave, 512 blocks). Per step, chain A's LDS h-exchange latency is
// hidden under chain B's FMA block and vice versa (2-stage software pipeline).
// __launch_bounds__(64,1) unlocks the 512-VGPR budget so the 60 W_hh values
// stay register-resident (R2's VGPR=68 showed they were being re-fetched).
// FMA chain in float2 form to invite v_pk_fma_f32.

#define T_STEPS 2048
#define B_ROWS  8192
#define NCHUNK  (T_STEPS / 8)

__device__ __forceinline__ float tanh_fast(float a) {
    // tanh(a) = 1 - 2/(exp(2a)+1); exp(2a) = exp2(a * 2*log2(e))
    float e = __builtin_amdgcn_exp2f(a * 2.8853900817779268f);
    float r = __builtin_amdgcn_rcpf(e + 1.0f);
    return fmaf(-2.0f, r, 1.0f);
}

__device__ __forceinline__ float2 fma2(float2 a, float2 b, float2 c) {
    return make_float2(fmaf(a.x, b.x, c.x), fmaf(a.y, b.y, c.y));
}

// Zero-instruction compiler ordering fence. HW DS pipe is in-order per wave,
// so intra-wave LDS write->read needs no s_waitcnt/barrier (verified R2).
#define LDS_FENCE() asm volatile("" ::: "memory")

struct Weights {
    float2 W2[3][10];            // W_hh rows for this lane's 3 j, k-pairs
    float  wi0[3], wi1[3], bsum[3];
};

struct Chain {
    float4 v0, v1, v2, v3, v4;   // h_t (20 values, full vector)
    float  hn0, hn1, hn2;        // lane-owned new h values
    float* hw;                   // LDS write slot
    const float* hr;             // LDS read base (row start)
};

__device__ __forceinline__ void chain_step(Chain& s, const Weights& w,
                                           float x0, float x1) {
    float2 c0 = make_float2(fmaf(x0, w.wi0[0], w.bsum[0]), x1 * w.wi1[0]);
    float2 c1 = make_float2(fmaf(x0, w.wi0[1], w.bsum[1]), x1 * w.wi1[1]);
    float2 c2 = make_float2(fmaf(x0, w.wi0[2], w.bsum[2]), x1 * w.wi1[2]);
#define PK(P, HX, HY) { const float2 h2 = make_float2(HX, HY); \
    c0 = fma2(h2, w.W2[0][P], c0); \
    c1 = fma2(h2, w.W2[1][P], c1); \
    c2 = fma2(h2, w.W2[2][P], c2); }
    PK(0, s.v0.x, s.v0.y) PK(1, s.v0.z, s.v0.w)
    PK(2, s.v1.x, s.v1.y) PK(3, s.v1.z, s.v1.w)
    PK(4, s.v2.x, s.v2.y) PK(5, s.v2.z, s.v2.w)
    PK(6, s.v3.x, s.v3.y) PK(7, s.v3.z, s.v3.w)
    PK(8, s.v4.x, s.v4.y) PK(9, s.v4.z, s.v4.w)
#undef PK
    s.hn0 = tanh_fast(c0.x + c0.y);
    s.hn1 = tanh_fast(c1.x + c1.y);
    s.hn2 = tanh_fast(c2.x + c2.y);
    s.hw[0] = s.hn0;
    s.hw[1] = s.hn1;
    s.hw[2] = s.hn2;
    LDS_FENCE();                 // reads below stay after these writes
}

__device__ __forceinline__ void chain_reload(Chain& s) {
    s.v0 = *(const float4*)(s.hr + 0);
    s.v1 = *(const float4*)(s.hr + 4);
    s.v2 = *(const float4*)(s.hr + 8);
    s.v3 = *(const float4*)(s.hr + 12);
    s.v4 = *(const float4*)(s.hr + 16);
    LDS_FENCE();                 // next step's writes stay after these reads
}

__global__ __launch_bounds__(64, 1) void rnn_fused(
    const float* __restrict__ x,      // [B, T, 2]
    const float* __restrict__ W_ih,   // [20, 2]
    const float* __restrict__ W_hh,   // [20, 20]
    const float* __restrict__ b_ih,   // [20]
    const float* __restrict__ b_hh,   // [20]
    const float* __restrict__ fc_w,   // [1, 20]
    const float* __restrict__ fc_b,   // [1]
    float* __restrict__ out)          // [8192] out, then [8192*20] h_state
{
    __shared__ __align__(16) float hbuf[16][24];  // rows 0..7 chain A, 8..15 chain B

    const int lane = threadIdx.x & 63;
    const int g    = lane & 7;        // owns j = 3g..3g+2
    const int r    = lane >> 3;       // row-in-octet
    const int rowA = blockIdx.x * 16 + r;
    const int rowB = rowA + 8;

    Weights w;
#pragma unroll
    for (int jj = 0; jj < 3; ++jj) {
        const int j = 3 * g + jj;
        const bool v = (j < 20);
#pragma unroll
        for (int kk = 0; kk < 10; ++kk) {
            w.W2[jj][kk].x = v ? W_hh[j * 20 + 2 * kk + 0] : 0.0f;
            w.W2[jj][kk].y = v ? W_hh[j * 20 + 2 * kk + 1] : 0.0f;
        }
        w.wi0[jj]  = v ? W_ih[j * 2 + 0] : 0.0f;
        w.wi1[jj]  = v ? W_ih[j * 2 + 1] : 0.0f;
        w.bsum[jj] = v ? (b_ih[j] + b_hh[j]) : 0.0f;
    }

    Chain A, B;
    A.v0 = A.v1 = A.v2 = A.v3 = A.v4 = make_float4(0, 0, 0, 0);
    B.v0 = B.v1 = B.v2 = B.v3 = B.v4 = make_float4(0, 0, 0, 0);
    A.hn0 = A.hn1 = A.hn2 = B.hn0 = B.hn1 = B.hn2 = 0.0f;
    A.hw = &hbuf[r][3 * g];      A.hr = &hbuf[r][0];
    B.hw = &hbuf[8 + r][3 * g];  B.hr = &hbuf[8 + r][0];

    // x: chunk c = steps 8c..8c+7 = 64 B = 4 float4 per row (octet broadcasts
    // the same cacheline -> no shuffles needed). Double-buffered 1 chunk ahead.
    const float4* xA = (const float4*)(x + (size_t)rowA * (T_STEPS * 2));
    const float4* xB = (const float4*)(x + (size_t)rowB * (T_STEPS * 2));

    float4 qA[4], qB[4], qAn[4], qBn[4];
#pragma unroll
    for (int q = 0; q < 4; ++q) { qA[q] = xA[q]; qB[q] = xB[q]; }

    for (int c = 0; c < NCHUNK; ++c) {
        const int cn = (c + 1 < NCHUNK) ? (c + 1) : c;  // clamped dummy prefetch
#pragma unroll
        for (int q = 0; q < 4; ++q) {
            qAn[q] = xA[4 * cn + q];
            qBn[q] = xB[4 * cn + q];
        }
#pragma unroll
        for (int s = 0; s < 8; ++s) {
            float ax0, ax1, bx0, bx1;
            if (s & 1) { ax0 = qA[s >> 1].z; ax1 = qA[s >> 1].w;
                         bx0 = qB[s >> 1].z; bx1 = qB[s >> 1].w; }
            else       { ax0 = qA[s >> 1].x; ax1 = qA[s >> 1].y;
                         bx0 = qB[s >> 1].x; bx1 = qB[s >> 1].y; }
            // 2-stage pipeline: A's LDS round trip hides under B's FMA block,
            // B's hides under next iteration's A FMA block.
            chain_step(A, w, ax0, ax1);
            chain_reload(A);
            chain_step(B, w, bx0, bx1);
            chain_reload(B);
        }
#pragma unroll
        for (int q = 0; q < 4; ++q) { qA[q] = qAn[q]; qB[q] = qBn[q]; }
    }

    // ---- epilogue ----
    const int j0 = 3 * g;
    {
        float* hsA = out + B_ROWS + (size_t)rowA * 20;
        if (j0 + 0 < 20) hsA[j0 + 0] = A.hn0;
        if (j0 + 1 < 20) hsA[j0 + 1] = A.hn1;
        if (j0 + 2 < 20) hsA[j0 + 2] = A.hn2;
        float* hsB = out + B_ROWS + (size_t)rowB * 20;
        if (j0 + 0 < 20) hsB[j0 + 0] = B.hn0;
        if (j0 + 1 < 20) hsB[j0 + 1] = B.hn1;
        if (j0 + 2 < 20) hsB[j0 + 2] = B.hn2;
    }
    if (g == 0) {
        // every lane holds the full h_T for its rows in v0..v4
        float fw[20];
#pragma unroll
        for (int k = 0; k < 20; ++k) fw[k] = fc_w[k];
        const float fb = fc_b[0];
        float pA = fb, pB = fb;
        const float* hA = (const float*)&A.v0;   // v0..v4 contiguous in struct
        const float* hB = (const float*)&B.v0;
#pragma unroll
        for (int k = 0; k < 20; ++k) {
            pA = fmaf(hA[k], fw[k], pA);
            pB = fmaf(hB[k], fw[k], pB);
        }
        out[rowA] = pA;
        out[rowB] = pB;
    }
}

extern "C" void kernel_launch(void* const* d_in, const int* in_sizes, int n_in,
                              void* d_out, int out_size, void* d_ws, size_t ws_size,
                              hipStream_t stream) {
    const float* x    = (const float*)d_in[0];
    const float* W_ih = (const float*)d_in[1];
    const float* W_hh = (const float*)d_in[2];
    const float* b_ih = (const float*)d_in[3];
    const float* b_hh = (const float*)d_in[4];
    const float* fc_w = (const float*)d_in[5];
    const float* fc_b = (const float*)d_in[6];
    float* out = (float*)d_out;

    // 512 blocks x 64 threads: one wave per block, 16 rows (2 chains) per wave
    rnn_fused<<<512, 64, 0, stream>>>(x, W_ih, W_hh, b_ih, b_hh, fc_w, fc_b, out);
}

// Round 4
// 591.876 us; speedup vs baseline: 1.3459x; 1.3459x over previous
//
#include <hip/hip_runtime.h>

// Tanh-RNN: B=8192, T=2048, I=2, H=20, FC(H->1) on last h.
// Round 4: 16 lanes/row (k-split), 4 rows/wave, 2048 waves = 2 waves/SIMD.
// R3 showed per-wave ILP works but costs waves (rows are the only parallelism);
// this round buys TLP instead: the co-resident partner wave hides the
// ~250-cyc serial path (FMA chain + tanh + LDS turnaround) per step.
// Lane (r,e,g): partial dots for j=3g..3g+2 over k-half e (10 k's, 30 FMA,
// no pad waste); partials merged via __shfl_xor(8); tanh redundant on both
// halves; e=0 writes h to LDS (e=1 writes to a dump row -> no exec juggling);
// each lane reads back only its own k-half (3 LDS reads).

#define T_STEPS 2048
#define B_ROWS  8192
#define NCHUNK  (T_STEPS / 8)

__device__ __forceinline__ float tanh_fast(float a) {
    // tanh(a) = 1 - 2/(exp(2a)+1); exp(2a) = exp2(a * 2*log2(e))
    float e = __builtin_amdgcn_exp2f(a * 2.8853900817779268f);
    float r = __builtin_amdgcn_rcpf(e + 1.0f);
    return fmaf(-2.0f, r, 1.0f);
}

// Zero-instruction compiler ordering fence. HW DS pipe is in-order per wave,
// so intra-wave LDS write->read needs no s_waitcnt/barrier (verified R2/R3).
#define LDS_FENCE() asm volatile("" ::: "memory")

// LDS h layout per row (stride 28 floats, 16B-aligned sections):
//   pos(j) = j      for j < 10   (k-half 0 at [0..10))
//   pos(j) = j + 2  for j >= 10  (k-half 1 at [12..22), pad j=20..23 -> 22..25)
__device__ __forceinline__ int hpos(int j) { return (j < 10) ? j : j + 2; }

__global__ __launch_bounds__(64, 2) void rnn_fused(
    const float* __restrict__ x,      // [B, T, 2]
    const float* __restrict__ W_ih,   // [20, 2]
    const float* __restrict__ W_hh,   // [20, 20]
    const float* __restrict__ b_ih,   // [20]
    const float* __restrict__ b_hh,   // [20]
    const float* __restrict__ fc_w,   // [1, 20]
    const float* __restrict__ fc_b,   // [1]
    float* __restrict__ out)          // [8192] out, then [8192*20] h_state
{
    __shared__ __align__(16) float hbuf[8][28];  // rows 0..3 live, 4..7 = e=1 dump

    const int lane = threadIdx.x & 63;
    const int g    = lane & 7;          // j-group: owns j = 3g..3g+2
    const int e    = (lane >> 3) & 1;   // k-half: k in [10e, 10e+10)
    const int r    = lane >> 4;         // row within wave, 0..3
    const int row  = blockIdx.x * 4 + r;

    // ---- per-lane constants ----
    float2 Wk[3][5];                    // W_hh[j, 10e+2kk .. +1]
    float  winit[3], badd[3];
#pragma unroll
    for (int jj = 0; jj < 3; ++jj) {
        const int j = 3 * g + jj;
        const bool v = (j < 20);
#pragma unroll
        for (int kk = 0; kk < 5; ++kk) {
            Wk[jj][kk].x = v ? W_hh[j * 20 + 10 * e + 2 * kk + 0] : 0.0f;
            Wk[jj][kk].y = v ? W_hh[j * 20 + 10 * e + 2 * kk + 1] : 0.0f;
        }
        winit[jj] = v ? W_ih[j * 2 + e] : 0.0f;               // e=0: W_ih[:,0], e=1: [:,1]
        badd[jj]  = (v && e == 0) ? (b_ih[j] + b_hh[j]) : 0.0f;
    }

    // h k-half in registers: e=0 holds h[0..10), e=1 holds h[10..20)
    float2 hh[5];
#pragma unroll
    for (int kk = 0; kk < 5; ++kk) hh[kk] = make_float2(0.0f, 0.0f);
    float hn0 = 0.0f, hn1 = 0.0f, hn2 = 0.0f;

    // LDS addresses (hoisted out of the loop)
    float* wp = &hbuf[(e ? 4 : 0) + r][0];            // e=1 writes go to dump rows
    const int p0 = hpos(3 * g + 0), p1 = hpos(3 * g + 1), p2 = hpos(3 * g + 2);
    const float* rp = &hbuf[r][e ? 12 : 0];           // this lane's k-half, 16B aligned

    const float4* xq = (const float4*)(x + (size_t)row * (T_STEPS * 2));

    float4 q[4], qn[4];
#pragma unroll
    for (int i = 0; i < 4; ++i) q[i] = xq[i];

    for (int c = 0; c < NCHUNK; ++c) {
        const int cn = (c + 1 < NCHUNK) ? (c + 1) : c;   // clamped dummy prefetch
#pragma unroll
        for (int i = 0; i < 4; ++i) qn[i] = xq[4 * cn + i];

#pragma unroll
        for (int s = 0; s < 8; ++s) {
            const float x0 = (s & 1) ? q[s >> 1].z : q[s >> 1].x;
            const float x1 = (s & 1) ? q[s >> 1].w : q[s >> 1].y;
            const float xs = e ? x1 : x0;             // 1 cndmask

            // partial dots over this lane's 10-k half
            float a0 = fmaf(xs, winit[0], badd[0]);
            float a1 = fmaf(xs, winit[1], badd[1]);
            float a2 = fmaf(xs, winit[2], badd[2]);
#pragma unroll
            for (int kk = 0; kk < 5; ++kk) {
                a0 = fmaf(hh[kk].x, Wk[0][kk].x, a0);
                a1 = fmaf(hh[kk].x, Wk[1][kk].x, a1);
                a2 = fmaf(hh[kk].x, Wk[2][kk].x, a2);
                a0 = fmaf(hh[kk].y, Wk[0][kk].y, a0);
                a1 = fmaf(hh[kk].y, Wk[1][kk].y, a1);
                a2 = fmaf(hh[kk].y, Wk[2][kk].y, a2);
            }
            // merge k-halves (partner = lane ^ 8)
            a0 += __shfl_xor(a0, 8, 64);
            a1 += __shfl_xor(a1, 8, 64);
            a2 += __shfl_xor(a2, 8, 64);

            hn0 = tanh_fast(a0);
            hn1 = tanh_fast(a1);
            hn2 = tanh_fast(a2);

            wp[p0] = hn0;                             // e=1 lands in dump rows
            wp[p1] = hn1;
            wp[p2] = hn2;
            LDS_FENCE();                              // reads stay after writes
            const float4 fa = *(const float4*)(rp + 0);
            const float4 fb = *(const float4*)(rp + 4);
            const float2 fw = *(const float2*)(rp + 8);
            hh[0] = make_float2(fa.x, fa.y);
            hh[1] = make_float2(fa.z, fa.w);
            hh[2] = make_float2(fb.x, fb.y);
            hh[3] = make_float2(fb.z, fb.w);
            hh[4] = fw;
            LDS_FENCE();                              // next writes stay after reads
        }
#pragma unroll
        for (int i = 0; i < 4; ++i) q[i] = qn[i];
    }

    // ---- epilogue ----
    // h_state: [1, B, H] flat at offset B_ROWS (e=0 lanes own the canonical h)
    if (e == 0) {
        float* hs = out + B_ROWS + (size_t)row * 20;
        const int j0 = 3 * g;
        if (j0 + 0 < 20) hs[j0 + 0] = hn0;
        if (j0 + 1 < 20) hs[j0 + 1] = hn1;
        if (j0 + 2 < 20) hs[j0 + 2] = hn2;
    }
    // FC: partial over this lane's k-half, merged with partner
    {
        float pfc = 0.0f;
#pragma unroll
        for (int kk = 0; kk < 5; ++kk) {
            const int k = 10 * e + 2 * kk;
            pfc = fmaf(hh[kk].x, fc_w[k + 0], pfc);
            pfc = fmaf(hh[kk].y, fc_w[k + 1], pfc);
        }
        pfc += __shfl_xor(pfc, 8, 64);
        if (e == 0 && g == 0) out[row] = pfc + fc_b[0];
    }
}

extern "C" void kernel_launch(void* const* d_in, const int* in_sizes, int n_in,
                              void* d_out, int out_size, void* d_ws, size_t ws_size,
                              hipStream_t stream) {
    const float* x    = (const float*)d_in[0];
    const float* W_ih = (const float*)d_in[1];
    const float* W_hh = (const float*)d_in[2];
    const float* b_ih = (const float*)d_in[3];
    const float* b_hh = (const float*)d_in[4];
    const float* fc_w = (const float*)d_in[5];
    const float* fc_b = (const float*)d_in[6];
    float* out = (float*)d_out;

    // 2048 blocks x 64 threads: 1 wave/block, 4 rows/wave -> 2 waves/SIMD
    rnn_fused<<<2048, 64, 0, stream>>>(x, W_ih, W_hh, b_ih, b_hh, fc_w, fc_b, out);
}